// Round 2
// baseline (9083.387 us; speedup 1.0000x reference)
//
#include <hip/hip_runtime.h>
#include <math.h>

// Problem constants (match reference file)
#define NNODES 100000
#define NEDGE  1600000
#define HD     64
#define INDIM  256

static constexpr size_t NP = (size_t)NNODES * HD;  // floats per [N,H] plane = 6.4M

// ---------------- wave helpers ----------------
__device__ __forceinline__ float wave_bsum(float v) {
#pragma unroll
  for (int m = 1; m < 64; m <<= 1) v += __shfl_xor(v, m, 64);
  return v;
}

// ---------------- arch-weight softmax coefficients ----------------
// wc layout:
//  [0..2]   softmax(as_seq0 row0)/3      (s1 from S0[0..2])
//  [3..5]   softmax(as_seq0 row1)/3      (s2 seq part from S1[0..2])
//  [6..9]   softmax(as_res0)/4           (s2 res part from S0[0..3])
//  [10..11] softmax(as_last_seq0)/2      (z0 from S2[0..1])
//  [12..14] softmax(as_last_res0 row0)/3 (z0 from S0[0,1,3])
//  [15..17] softmax(as_last_res0 row1)/3 (z0 from S1[0,1,3])
//  [18..20] softmax(as_seq1)/3           (t1 from T0[0..2])
//  [21..22] softmax(as_last_seq1)/2      (z1 from T1[0..1])
//  [23..25] softmax(as_last_res1)/3      (z1 from T0[0,1,3])
__global__ void wcoef_kernel(const float* __restrict__ s0, const float* __restrict__ ls0,
                             const float* __restrict__ r0, const float* __restrict__ lr0,
                             const float* __restrict__ s1, const float* __restrict__ ls1,
                             const float* __restrict__ lr1, float* __restrict__ wc) {
  if (threadIdx.x != 0 || blockIdx.x != 0) return;
  auto sm2 = [](const float* a, float* o, float sc) {
    float m = fmaxf(a[0], a[1]);
    float e0 = expf(a[0] - m), e1 = expf(a[1] - m);
    float inv = sc / (e0 + e1);
    o[0] = e0 * inv; o[1] = e1 * inv;
  };
  auto sm3 = [](const float* a, float* o, float sc) {
    float m = fmaxf(a[0], fmaxf(a[1], a[2]));
    float e0 = expf(a[0] - m), e1 = expf(a[1] - m), e2 = expf(a[2] - m);
    float inv = sc / (e0 + e1 + e2);
    o[0] = e0 * inv; o[1] = e1 * inv; o[2] = e2 * inv;
  };
  auto sm4 = [](const float* a, float* o, float sc) {
    float m = fmaxf(fmaxf(a[0], a[1]), fmaxf(a[2], a[3]));
    float e0 = expf(a[0] - m), e1 = expf(a[1] - m), e2 = expf(a[2] - m), e3 = expf(a[3] - m);
    float inv = sc / (e0 + e1 + e2 + e3);
    o[0] = e0 * inv; o[1] = e1 * inv; o[2] = e2 * inv; o[3] = e3 * inv;
  };
  sm3(s0,      wc + 0,  1.f / 3.f);
  sm3(s0 + 3,  wc + 3,  1.f / 3.f);
  sm4(r0,      wc + 6,  0.25f);
  sm2(ls0,     wc + 10, 0.5f);
  sm3(lr0,     wc + 12, 1.f / 3.f);
  sm3(lr0 + 3, wc + 15, 1.f / 3.f);
  sm3(s1,      wc + 18, 1.f / 3.f);
  sm2(ls1,     wc + 21, 0.5f);
  sm3(lr1,     wc + 23, 1.f / 3.f);
}

// ---------------- per-node typed projection + both affines ----------------
// hid = feats[n] @ type_W[t] + type_b[t]; x0 = hid@W0+b0; x1 = hid@W1+b1
// one wave per node, lane = output channel
__global__ __launch_bounds__(256) void hid_kernel(
    const float* __restrict__ feats, const int* __restrict__ types,
    const float* __restrict__ type_W, const float* __restrict__ type_b,
    const float* __restrict__ W0, const float* __restrict__ b0,
    const float* __restrict__ W1, const float* __restrict__ b1,
    float* __restrict__ x0, float* __restrict__ x1) {
  int wave = threadIdx.x >> 6, lane = threadIdx.x & 63;
  int n = blockIdx.x * 4 + wave;
  if (n >= NNODES) return;
  int t = types[n];
  const float* W = type_W + (size_t)t * INDIM * HD;
  const float* f = feats + (size_t)n * INDIM;
  float f0 = f[lane], f1 = f[64 + lane], f2 = f[128 + lane], f3 = f[192 + lane];
  float acc = type_b[t * HD + lane];
#pragma unroll 8
  for (int k = 0; k < 64; k++) acc = fmaf(__shfl(f0, k, 64), W[(k)*HD + lane], acc);
#pragma unroll 8
  for (int k = 0; k < 64; k++) acc = fmaf(__shfl(f1, k, 64), W[(64 + k) * HD + lane], acc);
#pragma unroll 8
  for (int k = 0; k < 64; k++) acc = fmaf(__shfl(f2, k, 64), W[(128 + k) * HD + lane], acc);
#pragma unroll 8
  for (int k = 0; k < 64; k++) acc = fmaf(__shfl(f3, k, 64), W[(192 + k) * HD + lane], acc);
  float a0 = b0[lane], a1 = b1[lane];
#pragma unroll 8
  for (int j = 0; j < 64; j++) {
    float hv = __shfl(acc, j, 64);
    a0 = fmaf(hv, W0[j * HD + lane], a0);
    a1 = fmaf(hv, W1[j * HD + lane], a1);
  }
  size_t o = (size_t)n * HD + lane;
  x0[o] = a0;
  x1[o] = a1;
}

// ---------------- SpMM stage 1: scatter x0/x1 into 5 combo accumulators ----------------
// blockIdx.y = adjacency; per edge (wave): gather x0[c],x1[c], weighted atomics to row r.
__global__ __launch_bounds__(256) void spmm1_kernel(
    const int* __restrict__ rows, const int* __restrict__ cols, const float* __restrict__ vals,
    const float* __restrict__ x0, const float* __restrict__ x1, const float* __restrict__ wc,
    float* __restrict__ cs1, float* __restrict__ cres, float* __restrict__ cz0,
    float* __restrict__ ct1, float* __restrict__ cz1) {
  int a = blockIdx.y;
  int gid = blockIdx.x * blockDim.x + threadIdx.x;
  int wave = gid >> 6, lane = gid & 63;
  int nw = (gridDim.x * blockDim.x) >> 6;
  const int* r = rows + (size_t)a * NEDGE;
  const int* c = cols + (size_t)a * NEDGE;
  const float* v = vals + (size_t)a * NEDGE;
  float w_s1  = (a < 3) ? wc[a] : 0.f;
  float w_res = wc[6 + a];
  float w_z0  = (a == 3) ? wc[14] : ((a < 2) ? wc[12 + a] : 0.f);
  float w_t1  = (a < 3) ? wc[18 + a] : 0.f;
  float w_z1  = (a == 3) ? wc[25] : ((a < 2) ? wc[23 + a] : 0.f);
  for (int e = wave; e < NEDGE; e += nw) {
    int rr = r[e], cc = c[e];
    float vv = v[e];
    size_t ci = (size_t)cc * HD + lane, ri = (size_t)rr * HD + lane;
    float g0 = vv * x0[ci];
    float g1 = vv * x1[ci];
    if (a < 3)  unsafeAtomicAdd(&cs1[ri], w_s1 * g0);
    unsafeAtomicAdd(&cres[ri], w_res * g0);
    if (a != 2) unsafeAtomicAdd(&cz0[ri], w_z0 * g0);
    if (a < 3)  unsafeAtomicAdd(&ct1[ri], w_t1 * g1);
    if (a != 2) unsafeAtomicAdd(&cz1[ri], w_z1 * g1);
  }
}

// ---------------- SpMM stage 2: scatter s1/t1; s2 seq part -> cres, plus z0/z1 ----------------
__global__ __launch_bounds__(256) void spmm2_kernel(
    const int* __restrict__ rows, const int* __restrict__ cols, const float* __restrict__ vals,
    const float* __restrict__ s1, const float* __restrict__ t1, const float* __restrict__ wc,
    float* __restrict__ cres, float* __restrict__ cz0, float* __restrict__ cz1) {
  int a = blockIdx.y;
  int gid = blockIdx.x * blockDim.x + threadIdx.x;
  int wave = gid >> 6, lane = gid & 63;
  int nw = (gridDim.x * blockDim.x) >> 6;
  const int* r = rows + (size_t)a * NEDGE;
  const int* c = cols + (size_t)a * NEDGE;
  const float* v = vals + (size_t)a * NEDGE;
  float w_seq = (a < 3) ? wc[3 + a] : 0.f;                            // S1 -> s2 (cres)
  float w_z0  = (a == 3) ? wc[17] : ((a < 2) ? wc[15 + a] : 0.f);     // S1 -> z0
  float w_z1  = (a < 2) ? wc[21 + a] : 0.f;                           // T1 -> z1
  for (int e = wave; e < NEDGE; e += nw) {
    int rr = r[e], cc = c[e];
    float vv = v[e];
    size_t ci = (size_t)cc * HD + lane, ri = (size_t)rr * HD + lane;
    float gs = vv * s1[ci];
    if (a < 3)  unsafeAtomicAdd(&cres[ri], w_seq * gs);
    if (a != 2) unsafeAtomicAdd(&cz0[ri], w_z0 * gs);
    if (a < 2) {
      float gt = vv * t1[ci];
      unsafeAtomicAdd(&cz1[ri], w_z1 * gt);
    }
  }
}

// ---------------- SpMM stage 3: scatter s2 (== cres) into z0, adjs 0,1 only ----------------
__global__ __launch_bounds__(256) void spmm3_kernel(
    const int* __restrict__ rows, const int* __restrict__ cols, const float* __restrict__ vals,
    const float* __restrict__ s2, const float* __restrict__ wc, float* __restrict__ cz0) {
  int a = blockIdx.y;  // 0..1
  int gid = blockIdx.x * blockDim.x + threadIdx.x;
  int wave = gid >> 6, lane = gid & 63;
  int nw = (gridDim.x * blockDim.x) >> 6;
  const int* r = rows + (size_t)a * NEDGE;
  const int* c = cols + (size_t)a * NEDGE;
  const float* v = vals + (size_t)a * NEDGE;
  float w = wc[10 + a];
  for (int e = wave; e < NEDGE; e += nw) {
    int rr = r[e], cc = c[e];
    float vv = v[e];
    size_t ci = (size_t)cc * HD + lane, ri = (size_t)rr * HD + lane;
    unsafeAtomicAdd(&cz0[ri], w * vv * s2[ci]);
  }
}

// ---------------- final: LN+gelu both cells, semantic attention, classifier ----------------
// one wave per node, lane = h
__global__ __launch_bounds__(256) void final_kernel(
    const float* __restrict__ cz0, const float* __restrict__ cz1,
    const float* __restrict__ attn1_W, const float* __restrict__ attn1_b,
    const float* __restrict__ attn2_W, const float* __restrict__ attn2_b,
    const float* __restrict__ cls_W, const float* __restrict__ cls_b,
    float* __restrict__ out) {
  int wave = threadIdx.x >> 6, lane = threadIdx.x & 63;
  int n = blockIdx.x * 4 + wave;
  if (n >= NNODES) return;
  size_t idx = (size_t)n * HD + lane;

  float z0 = cz0[idx];
  float z1 = cz1[idx];

  // layernorm (no affine) + exact gelu
  float m0 = wave_bsum(z0) * (1.f / 64.f);
  float dv0 = z0 - m0;
  float var0 = wave_bsum(dv0 * dv0) * (1.f / 64.f);
  float y0 = dv0 * rsqrtf(var0 + 1e-5f);
  float g0 = 0.5f * y0 * (1.f + erff(y0 * 0.70710678118654752f));

  float m1 = wave_bsum(z1) * (1.f / 64.f);
  float dv1 = z1 - m1;
  float var1 = wave_bsum(dv1 * dv1) * (1.f / 64.f);
  float y1 = dv1 * rsqrtf(var1 + 1e-5f);
  float g1 = 0.5f * y1 * (1.f + erff(y1 * 0.70710678118654752f));

  // attention scores: tanh(g @ attn1_W + b) @ attn2_W + b2
  float t0 = attn1_b[lane], t1 = attn1_b[lane];
#pragma unroll 8
  for (int j = 0; j < 64; j++) {
    float w = attn1_W[j * HD + lane];
    t0 = fmaf(__shfl(g0, j, 64), w, t0);
    t1 = fmaf(__shfl(g1, j, 64), w, t1);
  }
  t0 = tanhf(t0);
  t1 = tanhf(t1);
  float aw = attn2_W[lane];
  float a0 = wave_bsum(t0 * aw) + attn2_b[0];
  float a1 = wave_bsum(t1 * aw) + attn2_b[0];
  float mx = fmaxf(a0, a1);
  float e0 = expf(a0 - mx), e1 = expf(a1 - mx);
  float inv = 1.f / (e0 + e1);
  float p0 = e0 * inv, p1 = e1 * inv;
  float o = p0 * g0 + p1 * g1;

  // classifier: out[n][k] = sum_l o_l * cls_W[l*8+k] + cls_b[k]
#pragma unroll
  for (int k = 0; k < 8; k++) {
    float s = wave_bsum(o * cls_W[lane * 8 + k]);
    if (lane == k) out[(size_t)n * 8 + k] = s + cls_b[k];
  }
}

extern "C" void kernel_launch(void* const* d_in, const int* in_sizes, int n_in,
                              void* d_out, int out_size, void* d_ws, size_t ws_size,
                              hipStream_t stream) {
  const float* node_feats   = (const float*)d_in[0];
  const int*   node_types   = (const int*)d_in[1];
  const int*   adj_rows     = (const int*)d_in[2];
  const int*   adj_cols     = (const int*)d_in[3];
  const float* adj_vals     = (const float*)d_in[4];
  const float* type_W       = (const float*)d_in[5];
  const float* type_b       = (const float*)d_in[6];
  const float* aW0          = (const float*)d_in[7];
  const float* ab0          = (const float*)d_in[8];
  const float* aW1          = (const float*)d_in[9];
  const float* ab1          = (const float*)d_in[10];
  const float* as_seq0      = (const float*)d_in[11];
  const float* as_last_seq0 = (const float*)d_in[12];
  const float* as_res0      = (const float*)d_in[13];
  const float* as_last_res0 = (const float*)d_in[14];
  const float* as_seq1      = (const float*)d_in[15];
  const float* as_last_seq1 = (const float*)d_in[16];
  const float* as_last_res1 = (const float*)d_in[17];
  const float* attn1_W      = (const float*)d_in[18];
  const float* attn1_b      = (const float*)d_in[19];
  const float* attn2_W      = (const float*)d_in[20];
  const float* attn2_b      = (const float*)d_in[21];
  const float* cls_W        = (const float*)d_in[22];
  const float* cls_b        = (const float*)d_in[23];
  float* out = (float*)d_out;
  float* ws = (float*)d_ws;

  // workspace layout: 7 planes x 25.6 MB = 179.2 MB + 26 floats
  float* x0   = ws + 0 * NP;
  float* x1   = ws + 1 * NP;
  float* cs1  = ws + 2 * NP;  // s1
  float* ct1  = ws + 3 * NP;  // t1
  float* cres = ws + 4 * NP;  // s2 (res part stage1, seq part stage2)
  float* cz0  = ws + 5 * NP;  // z0 = out_seq + out_res (cell 0, pre-LN)
  float* cz1  = ws + 6 * NP;  // z1 (cell 1, pre-LN)
  float* wc   = ws + 7 * NP;  // 26 floats

  // zero the 5 atomic accumulator planes (ws is poisoned 0xAA each call)
  hipMemsetAsync(cs1, 0, 5 * NP * sizeof(float), stream);

  wcoef_kernel<<<1, 64, 0, stream>>>(as_seq0, as_last_seq0, as_res0, as_last_res0,
                                     as_seq1, as_last_seq1, as_last_res1, wc);

  hid_kernel<<<NNODES / 4, 256, 0, stream>>>(node_feats, node_types, type_W, type_b,
                                             aW0, ab0, aW1, ab1, x0, x1);

  spmm1_kernel<<<dim3(1024, 4), 256, 0, stream>>>(adj_rows, adj_cols, adj_vals,
                                                  x0, x1, wc, cs1, cres, cz0, ct1, cz1);

  spmm2_kernel<<<dim3(1024, 4), 256, 0, stream>>>(adj_rows, adj_cols, adj_vals,
                                                  cs1, ct1, wc, cres, cz0, cz1);

  spmm3_kernel<<<dim3(1024, 2), 256, 0, stream>>>(adj_rows, adj_cols, adj_vals,
                                                  cres, wc, cz0);

  final_kernel<<<NNODES / 4, 256, 0, stream>>>(cz0, cz1,
                                               attn1_W, attn1_b, attn2_W, attn2_b,
                                               cls_W, cls_b, out);
}

// Round 3
// 2514.021 us; speedup vs baseline: 3.6131x; 3.6131x over previous
//
#include <hip/hip_runtime.h>
#include <math.h>

// Problem constants (match reference file)
#define NNODES 100000
#define NEDGE  1600000
#define HD     64
#define INDIM  256

static constexpr size_t NP = (size_t)NNODES * HD;   // floats per [N,H] plane = 6.4M
static constexpr int    M4 = 4 * NNODES;            // 400000 (a,row) counters
static constexpr int    SCAN_BLOCKS = (M4 + 1023) / 1024;  // 391

// workspace layout (floats)
static constexpr size_t PLN_OFF  = 0;                    // 7 planes
static constexpr size_t WC_OFF   = 7 * NP;               // 26 floats (pad 32)
static constexpr size_t CNT_OFF  = WC_OFF + 32;          // M4 ints
static constexpr size_t RP_OFF   = CNT_OFF + M4;         // M4 ints
static constexpr size_t CUR_OFF  = RP_OFF + M4;          // M4 ints
static constexpr size_t PART_OFF = CUR_OFF + M4;         // 512 ints
static constexpr size_t EPK_OFF  = PART_OFF + 512;       // 6.4M int2 (even offset -> 8B aligned)
static constexpr size_t FAST_FLOATS = EPK_OFF + (size_t)2 * 4 * NEDGE;
static constexpr size_t FAST_NEED = FAST_FLOATS * 4;     // ~235.2 MB

// ---------------- wave helpers ----------------
__device__ __forceinline__ float wave_bsum(float v) {
#pragma unroll
  for (int m = 1; m < 64; m <<= 1) v += __shfl_xor(v, m, 64);
  return v;
}

// ---------------- arch-weight softmax coefficients ----------------
// wc layout:
//  [0..2]   softmax(as_seq0 row0)/3      (s1 from S0[0..2])
//  [3..5]   softmax(as_seq0 row1)/3      (s2 seq part from S1[0..2])
//  [6..9]   softmax(as_res0)/4           (s2 res part from S0[0..3])
//  [10..11] softmax(as_last_seq0)/2      (z0 from S2[0..1])
//  [12..14] softmax(as_last_res0 row0)/3 (z0 from S0[0,1,3])
//  [15..17] softmax(as_last_res0 row1)/3 (z0 from S1[0,1,3])
//  [18..20] softmax(as_seq1)/3           (t1 from T0[0..2])
//  [21..22] softmax(as_last_seq1)/2      (z1 from T1[0..1])
//  [23..25] softmax(as_last_res1)/3      (z1 from T0[0,1,3])
__global__ void wcoef_kernel(const float* __restrict__ s0, const float* __restrict__ ls0,
                             const float* __restrict__ r0, const float* __restrict__ lr0,
                             const float* __restrict__ s1, const float* __restrict__ ls1,
                             const float* __restrict__ lr1, float* __restrict__ wc) {
  if (threadIdx.x != 0 || blockIdx.x != 0) return;
  auto sm2 = [](const float* a, float* o, float sc) {
    float m = fmaxf(a[0], a[1]);
    float e0 = expf(a[0] - m), e1 = expf(a[1] - m);
    float inv = sc / (e0 + e1);
    o[0] = e0 * inv; o[1] = e1 * inv;
  };
  auto sm3 = [](const float* a, float* o, float sc) {
    float m = fmaxf(a[0], fmaxf(a[1], a[2]));
    float e0 = expf(a[0] - m), e1 = expf(a[1] - m), e2 = expf(a[2] - m);
    float inv = sc / (e0 + e1 + e2);
    o[0] = e0 * inv; o[1] = e1 * inv; o[2] = e2 * inv;
  };
  auto sm4 = [](const float* a, float* o, float sc) {
    float m = fmaxf(fmaxf(a[0], a[1]), fmaxf(a[2], a[3]));
    float e0 = expf(a[0] - m), e1 = expf(a[1] - m), e2 = expf(a[2] - m), e3 = expf(a[3] - m);
    float inv = sc / (e0 + e1 + e2 + e3);
    o[0] = e0 * inv; o[1] = e1 * inv; o[2] = e2 * inv; o[3] = e3 * inv;
  };
  sm3(s0,      wc + 0,  1.f / 3.f);
  sm3(s0 + 3,  wc + 3,  1.f / 3.f);
  sm4(r0,      wc + 6,  0.25f);
  sm2(ls0,     wc + 10, 0.5f);
  sm3(lr0,     wc + 12, 1.f / 3.f);
  sm3(lr0 + 3, wc + 15, 1.f / 3.f);
  sm3(s1,      wc + 18, 1.f / 3.f);
  sm2(ls1,     wc + 21, 0.5f);
  sm3(lr1,     wc + 23, 1.f / 3.f);
}

// ---------------- per-node typed projection + both affines ----------------
__global__ __launch_bounds__(256) void hid_kernel(
    const float* __restrict__ feats, const int* __restrict__ types,
    const float* __restrict__ type_W, const float* __restrict__ type_b,
    const float* __restrict__ W0, const float* __restrict__ b0,
    const float* __restrict__ W1, const float* __restrict__ b1,
    float* __restrict__ x0, float* __restrict__ x1) {
  int wave = threadIdx.x >> 6, lane = threadIdx.x & 63;
  int n = blockIdx.x * 4 + wave;
  if (n >= NNODES) return;
  int t = types[n];
  const float* W = type_W + (size_t)t * INDIM * HD;
  const float* f = feats + (size_t)n * INDIM;
  float f0 = f[lane], f1 = f[64 + lane], f2 = f[128 + lane], f3 = f[192 + lane];
  float acc = type_b[t * HD + lane];
#pragma unroll 8
  for (int k = 0; k < 64; k++) acc = fmaf(__shfl(f0, k, 64), W[(k)*HD + lane], acc);
#pragma unroll 8
  for (int k = 0; k < 64; k++) acc = fmaf(__shfl(f1, k, 64), W[(64 + k) * HD + lane], acc);
#pragma unroll 8
  for (int k = 0; k < 64; k++) acc = fmaf(__shfl(f2, k, 64), W[(128 + k) * HD + lane], acc);
#pragma unroll 8
  for (int k = 0; k < 64; k++) acc = fmaf(__shfl(f3, k, 64), W[(192 + k) * HD + lane], acc);
  float a0 = b0[lane], a1 = b1[lane];
#pragma unroll 8
  for (int j = 0; j < 64; j++) {
    float hv = __shfl(acc, j, 64);
    a0 = fmaf(hv, W0[j * HD + lane], a0);
    a1 = fmaf(hv, W1[j * HD + lane], a1);
  }
  size_t o = (size_t)n * HD + lane;
  x0[o] = a0;
  x1[o] = a1;
}

// ================= CSR build =================
__global__ __launch_bounds__(256) void hist_kernel(const int* __restrict__ rows,
                                                   int* __restrict__ counts) {
  int a = blockIdx.y;
  int e = blockIdx.x * 256 + threadIdx.x;
  int r = rows[(size_t)a * NEDGE + e];
  atomicAdd(&counts[a * NNODES + r], 1);
}

__global__ __launch_bounds__(256) void scan1_kernel(const int* __restrict__ counts,
                                                    int* __restrict__ rp,
                                                    int* __restrict__ partials) {
  __shared__ int sdata[256];
  int t = threadIdx.x;
  int base = blockIdx.x * 1024 + t * 4;
  int v0 = (base + 0 < M4) ? counts[base + 0] : 0;
  int v1 = (base + 1 < M4) ? counts[base + 1] : 0;
  int v2 = (base + 2 < M4) ? counts[base + 2] : 0;
  int v3 = (base + 3 < M4) ? counts[base + 3] : 0;
  int tsum = v0 + v1 + v2 + v3;
  sdata[t] = tsum;
  __syncthreads();
  for (int off = 1; off < 256; off <<= 1) {
    int x = (t >= off) ? sdata[t - off] : 0;
    __syncthreads();
    sdata[t] += x;
    __syncthreads();
  }
  int excl = sdata[t] - tsum;
  if (t == 255) partials[blockIdx.x] = sdata[255];
  if (base + 0 < M4) rp[base + 0] = excl;
  if (base + 1 < M4) rp[base + 1] = excl + v0;
  if (base + 2 < M4) rp[base + 2] = excl + v0 + v1;
  if (base + 3 < M4) rp[base + 3] = excl + v0 + v1 + v2;
}

__global__ __launch_bounds__(512) void scan2_kernel(int* __restrict__ partials) {
  __shared__ int sdata[512];
  int t = threadIdx.x;
  int v = (t < SCAN_BLOCKS) ? partials[t] : 0;
  sdata[t] = v;
  __syncthreads();
  for (int off = 1; off < 512; off <<= 1) {
    int x = (t >= off) ? sdata[t - off] : 0;
    __syncthreads();
    sdata[t] += x;
    __syncthreads();
  }
  if (t < SCAN_BLOCKS) partials[t] = sdata[t] - v;  // exclusive
}

__global__ __launch_bounds__(256) void scan3_kernel(int* __restrict__ rp,
                                                    const int* __restrict__ partials,
                                                    int* __restrict__ cursor) {
  int p = partials[blockIdx.x];
  int t = threadIdx.x;
#pragma unroll
  for (int j = 0; j < 4; j++) {
    int i = blockIdx.x * 1024 + j * 256 + t;
    if (i < M4) {
      int v = rp[i] + p;
      rp[i] = v;
      cursor[i] = v;
    }
  }
}

__global__ __launch_bounds__(256) void scatter_kernel(
    const int* __restrict__ rows, const int* __restrict__ cols, const float* __restrict__ vals,
    int* __restrict__ cursor, int2* __restrict__ epk) {
  int a = blockIdx.y;
  int e = blockIdx.x * 256 + threadIdx.x;
  size_t idx = (size_t)a * NEDGE + e;
  int r = rows[idx], c = cols[idx];
  float v = vals[idx];
  int pos = atomicAdd(&cursor[a * NNODES + r], 1);
  int2 pk;
  pk.x = c;
  pk.y = __float_as_int(v);
  epk[pos] = pk;
}

// ================= gather-based SpMM stages (no atomics) =================
// stage 1: gather x0/x1, write s1, t1, res(s2 part), z0 partial, z1 partial
__global__ __launch_bounds__(256) void gth1_kernel(
    const int* __restrict__ rp, const int* __restrict__ cnts, const int2* __restrict__ epk,
    const float* __restrict__ x0, const float* __restrict__ x1, const float* __restrict__ wc,
    float* __restrict__ cs1, float* __restrict__ ct1, float* __restrict__ cres,
    float* __restrict__ cz0, float* __restrict__ cz1) {
  int wave = threadIdx.x >> 6, lane = threadIdx.x & 63;
  int n = blockIdx.x * 4 + wave;
  if (n >= NNODES) return;
  float a_s1 = 0.f, a_res = 0.f, a_z0 = 0.f, a_t1 = 0.f, a_z1 = 0.f;
#pragma unroll
  for (int a = 0; a < 4; a++) {
    int base = rp[a * NNODES + n], cnt = cnts[a * NNODES + n];
    float s0 = 0.f, s1 = 0.f;
    int k = 0;
    for (; k + 2 <= cnt; k += 2) {
      int2 p0 = epk[base + k], p1 = epk[base + k + 1];
      size_t c0 = (size_t)p0.x * HD + lane, c1 = (size_t)p1.x * HD + lane;
      float v0 = __int_as_float(p0.y), v1 = __int_as_float(p1.y);
      float g00 = x0[c0], g01 = x1[c0], g10 = x0[c1], g11 = x1[c1];
      s0 = fmaf(v0, g00, s0); s1 = fmaf(v0, g01, s1);
      s0 = fmaf(v1, g10, s0); s1 = fmaf(v1, g11, s1);
    }
    if (k < cnt) {
      int2 p0 = epk[base + k];
      size_t c0 = (size_t)p0.x * HD + lane;
      float v0 = __int_as_float(p0.y);
      s0 = fmaf(v0, x0[c0], s0);
      s1 = fmaf(v0, x1[c0], s1);
    }
    float w_s1  = (a < 3) ? wc[a] : 0.f;
    float w_res = wc[6 + a];
    float w_z0  = (a == 3) ? wc[14] : ((a < 2) ? wc[12 + a] : 0.f);
    float w_t1  = (a < 3) ? wc[18 + a] : 0.f;
    float w_z1  = (a == 3) ? wc[25] : ((a < 2) ? wc[23 + a] : 0.f);
    a_s1 = fmaf(w_s1, s0, a_s1);
    a_res = fmaf(w_res, s0, a_res);
    a_z0 = fmaf(w_z0, s0, a_z0);
    a_t1 = fmaf(w_t1, s1, a_t1);
    a_z1 = fmaf(w_z1, s1, a_z1);
  }
  size_t o = (size_t)n * HD + lane;
  cs1[o] = a_s1;
  ct1[o] = a_t1;
  cres[o] = a_res;
  cz0[o] = a_z0;
  cz1[o] = a_z1;
}

// stage 2: gather cs1 (4 adjs) + ct1 (2 adjs); RMW cres->s2, cz0, cz1
__global__ __launch_bounds__(256) void gth2_kernel(
    const int* __restrict__ rp, const int* __restrict__ cnts, const int2* __restrict__ epk,
    const float* __restrict__ cs1, const float* __restrict__ ct1, const float* __restrict__ wc,
    float* __restrict__ cres, float* __restrict__ cz0, float* __restrict__ cz1) {
  int wave = threadIdx.x >> 6, lane = threadIdx.x & 63;
  int n = blockIdx.x * 4 + wave;
  if (n >= NNODES) return;
  float ss0 = 0.f, ss1 = 0.f, ss2 = 0.f, ss3 = 0.f, st0 = 0.f, st1 = 0.f;
#pragma unroll
  for (int a = 0; a < 4; a++) {
    int base = rp[a * NNODES + n], cnt = cnts[a * NNODES + n];
    float s = 0.f, t = 0.f;
    int k = 0;
    for (; k + 2 <= cnt; k += 2) {
      int2 p0 = epk[base + k], p1 = epk[base + k + 1];
      size_t c0 = (size_t)p0.x * HD + lane, c1 = (size_t)p1.x * HD + lane;
      float v0 = __int_as_float(p0.y), v1 = __int_as_float(p1.y);
      s = fmaf(v0, cs1[c0], s);
      s = fmaf(v1, cs1[c1], s);
      if (a < 2) {
        t = fmaf(v0, ct1[c0], t);
        t = fmaf(v1, ct1[c1], t);
      }
    }
    if (k < cnt) {
      int2 p0 = epk[base + k];
      size_t c0 = (size_t)p0.x * HD + lane;
      float v0 = __int_as_float(p0.y);
      s = fmaf(v0, cs1[c0], s);
      if (a < 2) t = fmaf(v0, ct1[c0], t);
    }
    if (a == 0) { ss0 = s; st0 = t; }
    else if (a == 1) { ss1 = s; st1 = t; }
    else if (a == 2) ss2 = s;
    else ss3 = s;
  }
  size_t o = (size_t)n * HD + lane;
  cres[o] = cres[o] + wc[3] * ss0 + wc[4] * ss1 + wc[5] * ss2;           // s2 = res + seq
  cz0[o]  = cz0[o]  + wc[15] * ss0 + wc[16] * ss1 + wc[17] * ss3;
  cz1[o]  = cz1[o]  + wc[21] * st0 + wc[22] * st1;
}

// stage 3: gather s2 (=cres) on adjs 0,1; add into cz0
__global__ __launch_bounds__(256) void gth3_kernel(
    const int* __restrict__ rp, const int* __restrict__ cnts, const int2* __restrict__ epk,
    const float* __restrict__ s2, const float* __restrict__ wc, float* __restrict__ cz0) {
  int wave = threadIdx.x >> 6, lane = threadIdx.x & 63;
  int n = blockIdx.x * 4 + wave;
  if (n >= NNODES) return;
  float acc = 0.f;
#pragma unroll
  for (int a = 0; a < 2; a++) {
    int base = rp[a * NNODES + n], cnt = cnts[a * NNODES + n];
    float s = 0.f;
    int k = 0;
    for (; k + 2 <= cnt; k += 2) {
      int2 p0 = epk[base + k], p1 = epk[base + k + 1];
      size_t c0 = (size_t)p0.x * HD + lane, c1 = (size_t)p1.x * HD + lane;
      s = fmaf(__int_as_float(p0.y), s2[c0], s);
      s = fmaf(__int_as_float(p1.y), s2[c1], s);
    }
    if (k < cnt) {
      int2 p0 = epk[base + k];
      s = fmaf(__int_as_float(p0.y), s2[(size_t)p0.x * HD + lane], s);
    }
    acc = fmaf(wc[10 + a], s, acc);
  }
  size_t o = (size_t)n * HD + lane;
  cz0[o] = cz0[o] + acc;
}

// ================= fallback atomic-scatter SpMM (round-2 proven path) =================
__global__ __launch_bounds__(256) void spmm1_kernel(
    const int* __restrict__ rows, const int* __restrict__ cols, const float* __restrict__ vals,
    const float* __restrict__ x0, const float* __restrict__ x1, const float* __restrict__ wc,
    float* __restrict__ cs1, float* __restrict__ cres, float* __restrict__ cz0,
    float* __restrict__ ct1, float* __restrict__ cz1) {
  int a = blockIdx.y;
  int gid = blockIdx.x * blockDim.x + threadIdx.x;
  int wave = gid >> 6, lane = gid & 63;
  int nw = (gridDim.x * blockDim.x) >> 6;
  const int* r = rows + (size_t)a * NEDGE;
  const int* c = cols + (size_t)a * NEDGE;
  const float* v = vals + (size_t)a * NEDGE;
  float w_s1  = (a < 3) ? wc[a] : 0.f;
  float w_res = wc[6 + a];
  float w_z0  = (a == 3) ? wc[14] : ((a < 2) ? wc[12 + a] : 0.f);
  float w_t1  = (a < 3) ? wc[18 + a] : 0.f;
  float w_z1  = (a == 3) ? wc[25] : ((a < 2) ? wc[23 + a] : 0.f);
  for (int e = wave; e < NEDGE; e += nw) {
    int rr = r[e], cc = c[e];
    float vv = v[e];
    size_t ci = (size_t)cc * HD + lane, ri = (size_t)rr * HD + lane;
    float g0 = vv * x0[ci];
    float g1 = vv * x1[ci];
    if (a < 3)  unsafeAtomicAdd(&cs1[ri], w_s1 * g0);
    unsafeAtomicAdd(&cres[ri], w_res * g0);
    if (a != 2) unsafeAtomicAdd(&cz0[ri], w_z0 * g0);
    if (a < 3)  unsafeAtomicAdd(&ct1[ri], w_t1 * g1);
    if (a != 2) unsafeAtomicAdd(&cz1[ri], w_z1 * g1);
  }
}

__global__ __launch_bounds__(256) void spmm2_kernel(
    const int* __restrict__ rows, const int* __restrict__ cols, const float* __restrict__ vals,
    const float* __restrict__ s1, const float* __restrict__ t1, const float* __restrict__ wc,
    float* __restrict__ cres, float* __restrict__ cz0, float* __restrict__ cz1) {
  int a = blockIdx.y;
  int gid = blockIdx.x * blockDim.x + threadIdx.x;
  int wave = gid >> 6, lane = gid & 63;
  int nw = (gridDim.x * blockDim.x) >> 6;
  const int* r = rows + (size_t)a * NEDGE;
  const int* c = cols + (size_t)a * NEDGE;
  const float* v = vals + (size_t)a * NEDGE;
  float w_seq = (a < 3) ? wc[3 + a] : 0.f;
  float w_z0  = (a == 3) ? wc[17] : ((a < 2) ? wc[15 + a] : 0.f);
  float w_z1  = (a < 2) ? wc[21 + a] : 0.f;
  for (int e = wave; e < NEDGE; e += nw) {
    int rr = r[e], cc = c[e];
    float vv = v[e];
    size_t ci = (size_t)cc * HD + lane, ri = (size_t)rr * HD + lane;
    float gs = vv * s1[ci];
    if (a < 3)  unsafeAtomicAdd(&cres[ri], w_seq * gs);
    if (a != 2) unsafeAtomicAdd(&cz0[ri], w_z0 * gs);
    if (a < 2) {
      float gt = vv * t1[ci];
      unsafeAtomicAdd(&cz1[ri], w_z1 * gt);
    }
  }
}

__global__ __launch_bounds__(256) void spmm3_kernel(
    const int* __restrict__ rows, const int* __restrict__ cols, const float* __restrict__ vals,
    const float* __restrict__ s2, const float* __restrict__ wc, float* __restrict__ cz0) {
  int a = blockIdx.y;
  int gid = blockIdx.x * blockDim.x + threadIdx.x;
  int wave = gid >> 6, lane = gid & 63;
  int nw = (gridDim.x * blockDim.x) >> 6;
  const int* r = rows + (size_t)a * NEDGE;
  const int* c = cols + (size_t)a * NEDGE;
  const float* v = vals + (size_t)a * NEDGE;
  float w = wc[10 + a];
  for (int e = wave; e < NEDGE; e += nw) {
    int rr = r[e], cc = c[e];
    float vv = v[e];
    size_t ci = (size_t)cc * HD + lane, ri = (size_t)rr * HD + lane;
    unsafeAtomicAdd(&cz0[ri], w * vv * s2[ci]);
  }
}

// ---------------- final: LN+gelu both cells, semantic attention, classifier ----------------
__global__ __launch_bounds__(256) void final_kernel(
    const float* __restrict__ cz0, const float* __restrict__ cz1,
    const float* __restrict__ attn1_W, const float* __restrict__ attn1_b,
    const float* __restrict__ attn2_W, const float* __restrict__ attn2_b,
    const float* __restrict__ cls_W, const float* __restrict__ cls_b,
    float* __restrict__ out) {
  int wave = threadIdx.x >> 6, lane = threadIdx.x & 63;
  int n = blockIdx.x * 4 + wave;
  if (n >= NNODES) return;
  size_t idx = (size_t)n * HD + lane;

  float z0 = cz0[idx];
  float z1 = cz1[idx];

  float m0 = wave_bsum(z0) * (1.f / 64.f);
  float dv0 = z0 - m0;
  float var0 = wave_bsum(dv0 * dv0) * (1.f / 64.f);
  float y0 = dv0 * rsqrtf(var0 + 1e-5f);
  float g0 = 0.5f * y0 * (1.f + erff(y0 * 0.70710678118654752f));

  float m1 = wave_bsum(z1) * (1.f / 64.f);
  float dv1 = z1 - m1;
  float var1 = wave_bsum(dv1 * dv1) * (1.f / 64.f);
  float y1 = dv1 * rsqrtf(var1 + 1e-5f);
  float g1 = 0.5f * y1 * (1.f + erff(y1 * 0.70710678118654752f));

  float t0 = attn1_b[lane], t1 = attn1_b[lane];
#pragma unroll 8
  for (int j = 0; j < 64; j++) {
    float w = attn1_W[j * HD + lane];
    t0 = fmaf(__shfl(g0, j, 64), w, t0);
    t1 = fmaf(__shfl(g1, j, 64), w, t1);
  }
  t0 = tanhf(t0);
  t1 = tanhf(t1);
  float aw = attn2_W[lane];
  float a0 = wave_bsum(t0 * aw) + attn2_b[0];
  float a1 = wave_bsum(t1 * aw) + attn2_b[0];
  float mx = fmaxf(a0, a1);
  float e0 = expf(a0 - mx), e1 = expf(a1 - mx);
  float inv = 1.f / (e0 + e1);
  float p0 = e0 * inv, p1 = e1 * inv;
  float o = p0 * g0 + p1 * g1;

#pragma unroll
  for (int k = 0; k < 8; k++) {
    float s = wave_bsum(o * cls_W[lane * 8 + k]);
    if (lane == k) out[(size_t)n * 8 + k] = s + cls_b[k];
  }
}

extern "C" void kernel_launch(void* const* d_in, const int* in_sizes, int n_in,
                              void* d_out, int out_size, void* d_ws, size_t ws_size,
                              hipStream_t stream) {
  const float* node_feats   = (const float*)d_in[0];
  const int*   node_types   = (const int*)d_in[1];
  const int*   adj_rows     = (const int*)d_in[2];
  const int*   adj_cols     = (const int*)d_in[3];
  const float* adj_vals     = (const float*)d_in[4];
  const float* type_W       = (const float*)d_in[5];
  const float* type_b       = (const float*)d_in[6];
  const float* aW0          = (const float*)d_in[7];
  const float* ab0          = (const float*)d_in[8];
  const float* aW1          = (const float*)d_in[9];
  const float* ab1          = (const float*)d_in[10];
  const float* as_seq0      = (const float*)d_in[11];
  const float* as_last_seq0 = (const float*)d_in[12];
  const float* as_res0      = (const float*)d_in[13];
  const float* as_last_res0 = (const float*)d_in[14];
  const float* as_seq1      = (const float*)d_in[15];
  const float* as_last_seq1 = (const float*)d_in[16];
  const float* as_last_res1 = (const float*)d_in[17];
  const float* attn1_W      = (const float*)d_in[18];
  const float* attn1_b      = (const float*)d_in[19];
  const float* attn2_W      = (const float*)d_in[20];
  const float* attn2_b      = (const float*)d_in[21];
  const float* cls_W        = (const float*)d_in[22];
  const float* cls_b        = (const float*)d_in[23];
  float* out = (float*)d_out;
  float* ws = (float*)d_ws;

  // 7 planes (x0,x1,cs1,ct1,cres,cz0,cz1) = 179.2 MB
  float* x0   = ws + 0 * NP;
  float* x1   = ws + 1 * NP;
  float* cs1  = ws + 2 * NP;
  float* ct1  = ws + 3 * NP;
  float* cres = ws + 4 * NP;
  float* cz0  = ws + 5 * NP;
  float* cz1  = ws + 6 * NP;
  float* wc   = ws + WC_OFF;

  wcoef_kernel<<<1, 64, 0, stream>>>(as_seq0, as_last_seq0, as_res0, as_last_res0,
                                     as_seq1, as_last_seq1, as_last_res1, wc);

  hid_kernel<<<NNODES / 4, 256, 0, stream>>>(node_feats, node_types, type_W, type_b,
                                             aW0, ab0, aW1, ab1, x0, x1);

  if (ws_size >= FAST_NEED) {
    // ---- CSR gather path (no atomics in SpMM) ----
    int*  counts   = (int*)(ws + CNT_OFF);
    int*  rp       = (int*)(ws + RP_OFF);
    int*  cursor   = (int*)(ws + CUR_OFF);
    int*  partials = (int*)(ws + PART_OFF);
    int2* epk      = (int2*)(ws + EPK_OFF);

    hipMemsetAsync(counts, 0, M4 * sizeof(int), stream);
    hist_kernel<<<dim3(NEDGE / 256, 4), 256, 0, stream>>>(adj_rows, counts);
    scan1_kernel<<<SCAN_BLOCKS, 256, 0, stream>>>(counts, rp, partials);
    scan2_kernel<<<1, 512, 0, stream>>>(partials);
    scan3_kernel<<<SCAN_BLOCKS, 256, 0, stream>>>(rp, partials, cursor);
    scatter_kernel<<<dim3(NEDGE / 256, 4), 256, 0, stream>>>(adj_rows, adj_cols, adj_vals,
                                                             cursor, epk);

    gth1_kernel<<<NNODES / 4, 256, 0, stream>>>(rp, counts, epk, x0, x1, wc,
                                                cs1, ct1, cres, cz0, cz1);
    gth2_kernel<<<NNODES / 4, 256, 0, stream>>>(rp, counts, epk, cs1, ct1, wc,
                                                cres, cz0, cz1);
    gth3_kernel<<<NNODES / 4, 256, 0, stream>>>(rp, counts, epk, cres, wc, cz0);
  } else {
    // ---- fallback: proven atomic-scatter path ----
    hipMemsetAsync(cs1, 0, 5 * NP * sizeof(float), stream);
    spmm1_kernel<<<dim3(1024, 4), 256, 0, stream>>>(adj_rows, adj_cols, adj_vals,
                                                    x0, x1, wc, cs1, cres, cz0, ct1, cz1);
    spmm2_kernel<<<dim3(1024, 4), 256, 0, stream>>>(adj_rows, adj_cols, adj_vals,
                                                    cs1, ct1, wc, cres, cz0, cz1);
    spmm3_kernel<<<dim3(1024, 2), 256, 0, stream>>>(adj_rows, adj_cols, adj_vals,
                                                    cres, wc, cz0);
  }

  final_kernel<<<NNODES / 4, 256, 0, stream>>>(cz0, cz1,
                                               attn1_W, attn1_b, attn2_W, attn2_b,
                                               cls_W, cls_b, out);
}